// Round 7
// baseline (187.172 us; speedup 1.0000x reference)
//
#include <hip/hip_runtime.h>
#include <cstdint>

#define DM    768
#define DI    1536
#define PP    64
#define HH    24
#define NN    64
#define CONVD 1664
#define DINP  3224
#define NP1   3328   // 3224 padded to 26*128
#define LL    1024
#define ROWS  2048   // BATCH*LL
#define EPSF  1e-5f
#define NCHUNK 16
#define CLEN   64
#define CSTRIPE 208

typedef unsigned short ushortT;
typedef __attribute__((ext_vector_type(8))) __bf16 bf16x8;
typedef __attribute__((ext_vector_type(8))) unsigned short ushort8;
typedef __attribute__((ext_vector_type(4))) unsigned short ushort4v;
typedef __attribute__((ext_vector_type(4))) float f32x4;

__device__ __forceinline__ int seqmap(int t) { return 1023 - 32 * (t & 31) - (t >> 5); }

__device__ __forceinline__ ushortT f2bf(float f) {
  union { float f; unsigned u; } v; v.f = f;
  unsigned r = v.u + 0x7FFF + ((v.u >> 16) & 1);
  return (ushortT)(r >> 16);
}
__device__ __forceinline__ float bf2f(ushortT b) {
  union { unsigned u; float f; } v; v.u = ((unsigned)b) << 16;
  return v.f;
}

__device__ __forceinline__ void gload_lds16(const void* g, void* l) {
  __builtin_amdgcn_global_load_lds((const __attribute__((address_space(1))) void*)g,
                                   (__attribute__((address_space(3))) void*)l, 16, 0, 0);
}

// swizzled ushort index into a 64x64 bf16 tile (row stride 64)
#define SWZ(r, c) ((r) * 64 + ((c) ^ (((r) & 7) << 3)))
// swizzled ushort index into a [128][64] bf16 tile (row stride 64)
#define SWZ64(r, c) ((r) * 64 + ((c) ^ (((r) & 7) << 3)))

// ---------------- merged weight convert (f32 -> bf16, zero-pad tail), vectorized ----------------
__global__ __launch_bounds__(256) void cvt_all_kernel(
    const float* __restrict__ fw1, const float* __restrict__ bw1,
    const float* __restrict__ fw2, const float* __restrict__ bw2,
    ushortT* __restrict__ WP1, ushortT* __restrict__ W2) {
  const long NW1 = (long)NP1 * DM, SW1 = (long)DINP * DM, NW2 = (long)DM * DI;
  const long tot8 = (2 * NW1 + 2 * NW2) >> 3;
  for (long i8 = (long)blockIdx.x * 256 + threadIdx.x; i8 < tot8; i8 += (long)gridDim.x * 256) {
    long i = i8 << 3;
    const float* src = nullptr;
    ushortT* dst;
    if (i < NW1) {
      if (i < SW1) src = fw1 + i;
      dst = WP1 + i;
    } else if (i < 2 * NW1) {
      long j = i - NW1;
      if (j < SW1) src = bw1 + j;
      dst = WP1 + i;
    } else if (i < 2 * NW1 + NW2) {
      long j = i - 2 * NW1;
      src = fw2 + j;
      dst = W2 + j;
    } else {
      long j = i - 2 * NW1 - NW2;
      src = bw2 + j;
      dst = W2 + NW2 + j;
    }
    ushort8 o = {};
    if (src) {
      float4 a = *(const float4*)src;
      float4 b2 = *(const float4*)(src + 4);
      o[0] = f2bf(a.x);  o[1] = f2bf(a.y);  o[2] = f2bf(a.z);  o[3] = f2bf(a.w);
      o[4] = f2bf(b2.x); o[5] = f2bf(b2.y); o[6] = f2bf(b2.z); o[7] = f2bf(b2.w);
    }
    *(ushort8*)dst = o;
  }
}

// ---------------- LayerNorm (both dirs; dir1 gathers via SEQ) ----------------
__global__ __launch_bounds__(256) void ln_kernel(const float* __restrict__ x,
    const float* __restrict__ wf, const float* __restrict__ bf_,
    const float* __restrict__ wb, const float* __restrict__ bb,
    ushortT* __restrict__ xln) {
  __shared__ float lds[4];
  int bid = blockIdx.x;
  int dir = bid >> 11, row = bid & 2047;
  int b = row >> 10, t = row & 1023;
  int st = dir ? seqmap(t) : t;
  const float* xr = x + (size_t)(b * 1024 + st) * DM;
  const float* w = dir ? wb : wf;
  const float* bia = dir ? bb : bf_;
  int tid = threadIdx.x;
  float v0 = xr[tid], v1 = xr[tid + 256], v2 = xr[tid + 512];
  float s = v0 + v1 + v2;
  #pragma unroll
  for (int o = 32; o; o >>= 1) s += __shfl_xor(s, o, 64);
  if ((tid & 63) == 0) lds[tid >> 6] = s;
  __syncthreads();
  float mean = (lds[0] + lds[1] + lds[2] + lds[3]) * (1.f / 768.f);
  __syncthreads();
  float d0 = v0 - mean, d1 = v1 - mean, d2 = v2 - mean;
  float q = d0 * d0 + d1 * d1 + d2 * d2;
  #pragma unroll
  for (int o = 32; o; o >>= 1) q += __shfl_xor(q, o, 64);
  if ((tid & 63) == 0) lds[tid >> 6] = q;
  __syncthreads();
  float var = (lds[0] + lds[1] + lds[2] + lds[3]) * (1.f / 768.f);
  float rs = rsqrtf(var + EPSF);
  ushortT* orow = xln + (size_t)bid * DM;
  orow[tid]       = f2bf(d0 * rs * w[tid]       + bia[tid]);
  orow[tid + 256] = f2bf(d1 * rs * w[tid + 256] + bia[tid + 256]);
  orow[tid + 512] = f2bf(d2 * rs * w[tid + 512] + bia[tid + 512]);
}

// ---------------- bf16 MFMA GEMM: C[M,N] = A[M,K] * B[N,K]^T ----------------
// BK=64, 3-stage LDS ring with prefetch distance 2, counted vmcnt + raw barriers,
// T2 both-sides swizzle, T1 XCD-aware block swizzle.
// MODE 0: bf16 output to Cb. MODE 1: bf16 to Cb for n0<3200, f32 to Cf (dt tail, ld 128).
template<int MODE>
__global__ __launch_bounds__(256) void gemm_bf16(
    const ushortT* __restrict__ Aall, const ushortT* __restrict__ Ball,
    float* __restrict__ Cfall, ushortT* __restrict__ Cball,
    int K, int lda, int ldb, int ldc, long sA, long sB, long sCf, long sCb) {
  __shared__ ushortT sA3[3][128 * 64];
  __shared__ ushortT sB3[3][128 * 64];
  // T1: XCD-aware remap of flat block id (nwg % 8 == 0 for both launches)
  int gx = gridDim.x, gy = gridDim.y;
  int nwg = gx * gy * gridDim.z;
  int lid = blockIdx.x + gx * (blockIdx.y + gy * blockIdx.z);
  int cpx = nwg >> 3;
  int swz = (lid & 7) * cpx + (lid >> 3);
  int bx = swz % gx;
  int rest = swz / gx;
  int by = rest % gy, bz = rest / gy;
  const ushortT* A = Aall + (size_t)bz * sA;
  const ushortT* B = Ball + (size_t)bz * sB;
  int tid = threadIdx.x, lane = tid & 63, w = tid >> 6;
  int wm = w >> 1, wn = w & 1;
  int m0 = by * 128, n0 = bx * 128;
  int rA8 = lane >> 3;
  int cSw = ((lane & 7) << 3) ^ (((lane >> 3) & 7) << 3);   // pre-swizzled source col
  f32x4 acc[4][4] = {};
  const int NT = K >> 6;
  int fr = lane & 15, kq = lane >> 4;

  auto STAGE = [&](int bf, int kt) {
    int kc = kt * 64 + cSw;
    #pragma unroll
    for (int c2 = 0; c2 < 4; ++c2) {
      int q = w * 4 + c2;
      gload_lds16(A + (size_t)(m0 + q * 8 + rA8) * lda + kc, &sA3[bf][q * 512]);
    }
    #pragma unroll
    for (int c2 = 0; c2 < 4; ++c2) {
      int q = w * 4 + c2;
      gload_lds16(B + (size_t)(n0 + q * 8 + rA8) * ldb + kc, &sB3[bf][q * 512]);
    }
  };

  STAGE(0, 0);
  if (NT > 1) STAGE(1, 1);
  for (int kt = 0; kt < NT; ++kt) {
    if (kt + 2 < NT) {
      STAGE((kt + 2) % 3, kt + 2);
      asm volatile("s_waitcnt vmcnt(16)" ::: "memory");   // tile kt's 8 loads done
    } else if (kt + 2 == NT) {
      asm volatile("s_waitcnt vmcnt(8)" ::: "memory");
    } else {
      asm volatile("s_waitcnt vmcnt(0)" ::: "memory");
    }
    __builtin_amdgcn_s_barrier();                         // all waves' tile-kt loads done
    __builtin_amdgcn_sched_barrier(0);
    int cur = kt % 3;
    #pragma unroll
    for (int ks = 0; ks < 2; ++ks) {
      int kb = ks * 32 + kq * 8;
      bf16x8 af[4], bfr[4];
      #pragma unroll
      for (int i = 0; i < 4; ++i)
        af[i] = *(const bf16x8*)&sA3[cur][SWZ64(wm * 64 + i * 16 + fr, kb)];
      #pragma unroll
      for (int j = 0; j < 4; ++j)
        bfr[j] = *(const bf16x8*)&sB3[cur][SWZ64(wn * 64 + j * 16 + fr, kb)];
      #pragma unroll
      for (int i = 0; i < 4; ++i)
        #pragma unroll
        for (int j = 0; j < 4; ++j)
          acc[i][j] = __builtin_amdgcn_mfma_f32_16x16x32_bf16(af[i], bfr[j], acc[i][j], 0, 0, 0);
    }
    asm volatile("s_waitcnt lgkmcnt(0)" ::: "memory");    // my LDS reads consumed
    __builtin_amdgcn_sched_barrier(0);
    __builtin_amdgcn_s_barrier();                         // safe to overwrite buf next iter
  }
  int cr = (lane >> 4) * 4, cc = lane & 15;
  if (MODE == 1 && n0 >= 3200) {
    float* Cf = Cfall + (size_t)bz * sCf;
    #pragma unroll
    for (int i = 0; i < 4; ++i)
      #pragma unroll
      for (int j = 0; j < 4; ++j) {
        float* Cp = Cf + (size_t)(m0 + wm * 64 + i * 16 + cr) * 128 + (wn * 64 + j * 16 + cc);
        #pragma unroll
        for (int r = 0; r < 4; ++r) Cp[(size_t)r * 128] = acc[i][j][r];
      }
  } else {
    ushortT* Cb = Cball + (size_t)bz * sCb;
    #pragma unroll
    for (int i = 0; i < 4; ++i)
      #pragma unroll
      for (int j = 0; j < 4; ++j) {
        ushortT* Cp = Cb + (size_t)(m0 + wm * 64 + i * 16 + cr) * ldc + (n0 + wn * 64 + j * 16 + cc);
        #pragma unroll
        for (int r = 0; r < 4; ++r) Cp[(size_t)r * ldc] = f2bf(acc[i][j][r]);
      }
  }
}

// ---------------- conv(K=4 causal, depthwise) + silu + dt/logdA, LDS-staged ----------------
// grid: (stripe 0..7, chunk 0..15, dirb 0..3); each block: 64 t x 208 channels.
__global__ __launch_bounds__(256) void conv_dt_kernel(const ushortT* __restrict__ zxb,
    const float* __restrict__ dtt,
    const float* __restrict__ cwf, const float* __restrict__ cbf,
    const float* __restrict__ cwb, const float* __restrict__ cbb,
    const float* __restrict__ dtbf, const float* __restrict__ alogf,
    const float* __restrict__ dtbb, const float* __restrict__ alogb,
    ushortT* __restrict__ xcb, float* __restrict__ dts, float* __restrict__ lda_) {
  __shared__ ushortT sZ[67][CSTRIPE];
  int stripe = blockIdx.x, chunk = blockIdx.y, dirb = blockIdx.z;
  int dir = dirb >> 1;
  int t0 = chunk * 64;
  size_t rowb = (size_t)dirb * 1024;
  const float* cw = dir ? cwb : cwf;
  const float* cb = dir ? cbb : cbf;
  int tid = threadIdx.x;
  int cbase = stripe * CSTRIPE;
  for (int idx = tid; idx < 67 * 26; idx += 256) {
    int r = idx / 26, u = idx % 26;
    int t = t0 - 3 + r;
    ushort8 v = {};
    if (t >= 0)
      v = *(const ushort8*)&zxb[(rowb + t) * NP1 + 1536 + cbase + u * 8];
    *(ushort8*)&sZ[r][u * 8] = v;
  }
  if (stripe == 0) {
    const float* dtb  = dir ? dtbb : dtbf;
    const float* alog = dir ? alogb : alogf;
    for (int i = tid; i < 64 * HH; i += 256) {
      int tt = i / HH, h = i % HH;
      size_t row = rowb + t0 + tt;
      float raw = dtt[row * 128 + h] + dtb[h];
      float dtv = raw > 20.f ? raw : log1pf(expf(raw));
      dts[row * HH + h] = dtv;
      lda_[row * HH + h] = -expf(alog[h]) * dtv;
    }
  }
  __syncthreads();
  for (int idx = tid; idx < 64 * 26; idx += 256) {
    int r = idx / 26, u = idx % 26;
    int c0 = cbase + u * 8;
    ushort8 x0 = *(const ushort8*)&sZ[r][u * 8];
    ushort8 x1 = *(const ushort8*)&sZ[r + 1][u * 8];
    ushort8 x2 = *(const ushort8*)&sZ[r + 2][u * 8];
    ushort8 x3 = *(const ushort8*)&sZ[r + 3][u * 8];
    ushort8 o;
    #pragma unroll
    for (int e = 0; e < 8; ++e) {
      int c = c0 + e;
      float acc = cb[c] + bf2f(x0[e]) * cw[c * 4 + 0] + bf2f(x1[e]) * cw[c * 4 + 1]
                + bf2f(x2[e]) * cw[c * 4 + 2] + bf2f(x3[e]) * cw[c * 4 + 3];
      o[e] = f2bf(acc / (1.f + expf(-acc)));
    }
    *(ushort8*)&xcb[(rowb + t0 + r) * CONVD + c0] = o;
  }
}

// ---------------- pass 1 (SSD form): block per (gh, chunk) ----------------
__global__ __launch_bounds__(256) void ssd_chunk_kernel(const ushortT* __restrict__ xcb,
    const float* __restrict__ dts, const float* __restrict__ lda_,
    ushortT* __restrict__ yb, ushortT* __restrict__ slocb, float* __restrict__ cwg,
    ushortT* __restrict__ cbg) {
  __shared__ ushortT sCb[4096];   // [t][n]
  __shared__ ushortT sBb[4096];   // [s][n]
  __shared__ ushortT sBT[4096];   // [n][t]  (weighted)
  __shared__ ushortT sXT[4096];   // [p][t]
  __shared__ ushortT sMb[4096];   // [t][s]
  __shared__ float clog[64];
  __shared__ float dt64[64];
  __shared__ float wv64[64];
  int gh = blockIdx.x;                 // dir*48 + b*24 + h
  int c  = blockIdx.y;                 // chunk
  int dir = gh / 48;
  int rem = gh % 48;
  int b = rem / 24, h = rem % 24;
  int tid = threadIdx.x, lane = tid & 63;
  int w = tid >> 6;
  size_t rowbase = ((size_t)dir * 2 + b) * 1024;
  size_t trow = rowbase + (size_t)c * CLEN;

  // ---- phase 1: stage C, B (ushort8); X^T via b64 vectorized transpose ----
  #pragma unroll
  for (int it2 = 0; it2 < 2; ++it2) {
    int idx2 = it2 * 256 + tid;
    int r = idx2 >> 3, c8 = (idx2 & 7) << 3;
    const ushortT* xrow = xcb + (trow + r) * CONVD;
    *(ushort8*)&sCb[SWZ(r, c8)] = *(const ushort8*)&xrow[1600 + c8];
    *(ushort8*)&sBb[SWZ(r, c8)] = *(const ushort8*)&xrow[1536 + c8];
  }
  {
    int p = lane;
    #pragma unroll
    for (int q = 0; q < 4; ++q) {
      int t4 = w * 16 + q * 4;
      ushortT a0 = xcb[(trow + t4 + 0) * CONVD + h * 64 + p];
      ushortT a1 = xcb[(trow + t4 + 1) * CONVD + h * 64 + p];
      ushortT a2 = xcb[(trow + t4 + 2) * CONVD + h * 64 + p];
      ushortT a3 = xcb[(trow + t4 + 3) * CONVD + h * 64 + p];
      int cT = t4 ^ ((p & 7) << 3);
      ushort4v v4 = {a0, a1, a2, a3};
      *(ushort4v*)&sXT[p * 64 + cT] = v4;
    }
  }
  if (tid < 64) {
    float ld = lda_[(trow + tid) * HH + h];
    float dtv = dts[(trow + tid) * HH + h];
    float v = ld;
    #pragma unroll
    for (int o = 1; o < 64; o <<= 1) {
      float u = __shfl_up(v, o, 64);
      if (tid >= o) v += u;
    }
    float tot = __shfl(v, 63, 64);
    clog[tid] = v;
    dt64[tid] = dtv;
    wv64[tid] = dtv * __expf(tot - v);
    cwg[(trow + tid) * HH + h] = __expf(v);
  }
  __syncthreads();

  // dump C tile once per (dir,b,chunk) for the fixup pass
  if (h == 0) {
    ushortT* dst = cbg + ((size_t)((dir * 2 + b) * NCHUNK + c)) * 4096;
    for (int idx = tid; idx < 4096; idx += 256) dst[idx] = sCb[idx];
  }

  int fr = lane & 15, kq = lane >> 4;

  // ---- phase 2: weighted B^T (b64 transpose); G = C.B^T; decay -> M(bf16) ----
  {
    int n = lane;
    #pragma unroll
    for (int q = 0; q < 4; ++q) {
      int s4 = w * 16 + q * 4;
      float b0 = bf2f(sBb[SWZ(s4 + 0, n)]) * wv64[s4 + 0];
      float b1 = bf2f(sBb[SWZ(s4 + 1, n)]) * wv64[s4 + 1];
      float b2 = bf2f(sBb[SWZ(s4 + 2, n)]) * wv64[s4 + 2];
      float b3 = bf2f(sBb[SWZ(s4 + 3, n)]) * wv64[s4 + 3];
      int cT = s4 ^ ((n & 7) << 3);
      ushort4v v4 = {f2bf(b0), f2bf(b1), f2bf(b2), f2bf(b3)};
      *(ushort4v*)&sBT[n * 64 + cT] = v4;
    }
  }
  f32x4 accG[4] = {};
  #pragma unroll
  for (int kt = 0; kt < 2; ++kt) {
    int kk = kt * 32 + kq * 8;
    bf16x8 af = *(const bf16x8*)&sCb[SWZ(w * 16 + fr, kk)];
    #pragma unroll
    for (int j = 0; j < 4; ++j) {
      bf16x8 bf_ = *(const bf16x8*)&sBb[SWZ(j * 16 + fr, kk)];
      accG[j] = __builtin_amdgcn_mfma_f32_16x16x32_bf16(af, bf_, accG[j], 0, 0, 0);
    }
  }
  #pragma unroll
  for (int j = 0; j < 4; ++j) {
    int s = j * 16 + fr;
    float cls = clog[s], dtv = dt64[s];
    #pragma unroll
    for (int r = 0; r < 4; ++r) {
      int t = w * 16 + kq * 4 + r;
      float dec = (s <= t) ? __expf(clog[t] - cls) * dtv : 0.f;
      sMb[SWZ(t, s)] = f2bf(accG[j][r] * dec);
    }
  }
  __syncthreads();

  // ---- phase 3: Y = M.X ; S = wB^T.X (shared X fragments) ----
  f32x4 accY[4] = {}, accS[4] = {};
  #pragma unroll
  for (int kt = 0; kt < 2; ++kt) {
    int kk = kt * 32 + kq * 8;
    bf16x8 aM = *(const bf16x8*)&sMb[SWZ(w * 16 + fr, kk)];
    bf16x8 aB = *(const bf16x8*)&sBT[SWZ(w * 16 + fr, kk)];
    #pragma unroll
    for (int j = 0; j < 4; ++j) {
      bf16x8 bx = *(const bf16x8*)&sXT[SWZ(j * 16 + fr, kk)];
      accY[j] = __builtin_amdgcn_mfma_f32_16x16x32_bf16(aM, bx, accY[j], 0, 0, 0);
      accS[j] = __builtin_amdgcn_mfma_f32_16x16x32_bf16(aB, bx, accS[j], 0, 0, 0);
    }
  }
  ushortT* spb = slocb + ((size_t)gh * NCHUNK + c) * 4096;
  #pragma unroll
  for (int j = 0; j < 4; ++j) {
    #pragma unroll
    for (int r = 0; r < 4; ++r) {
      int t = w * 16 + kq * 4 + r;        // row (t for Y, n for S)
      int p = j * 16 + fr;                // col
      yb[(trow + t) * DI + h * 64 + p] = f2bf(accY[j][r]);
      spb[t * 64 + p] = f2bf(accS[j][r]);
    }
  }
}

// ---------------- pass 2: serial prefix over chunk states (96 blocks) ----------------
__global__ __launch_bounds__(256) void chunk_prefix_kernel(
    const ushortT* __restrict__ slocb, const float* __restrict__ cwg,
    ushortT* __restrict__ sinitb) {
  __shared__ float ldsT[64 * 65];
  int gh = blockIdx.x;
  int dir = gh / 48;
  int rem = gh % 48;
  int b = rem / 24, h = rem % 24;
  int tid = threadIdx.x;
  size_t rowbase = ((size_t)dir * 2 + b) * 1024;
  float R[16];
  #pragma unroll
  for (int j = 0; j < 16; ++j) R[j] = 0.f;
  for (int c = 1; c < NCHUNK; ++c) {
    float W = cwg[(rowbase + (size_t)c * CLEN - 1) * HH + h];
    const ushortT* slot = slocb + ((size_t)gh * NCHUNK + (c - 1)) * 4096;
    #pragma unroll
    for (int j = 0; j < 16; ++j) {
      int idx = j * 256 + tid, n = idx >> 6, p = idx & 63;
      R[j] = __builtin_fmaf(R[j], W, bf2f(slot[idx]));
      ldsT[n * 65 + p] = R[j];
    }
    __syncthreads();
    ushortT* outp = sinitb + ((size_t)gh * (NCHUNK - 1) + (c - 1)) * 4096;
    #pragma unroll
    for (int j = 0; j < 16; ++j) {
      int idx = j * 256 + tid, p = idx >> 6, n = idx & 63;
      outp[SWZ(p, n)] = f2bf(ldsT[n * 65 + p]);
    }
    __syncthreads();
  }
}

// ---------------- pass 3 (MFMA): YI[t,p] = cw[t] * (C_t . S_init) ----------------
__global__ __launch_bounds__(256) void fixup_kernel(
    const ushortT* __restrict__ cbg, const ushortT* __restrict__ sinitb,
    const float* __restrict__ cwg, ushortT* __restrict__ yib) {
  __shared__ ushortT sCb[4096];
  __shared__ ushortT sST[4096];
  int gh = blockIdx.x;
  int c = blockIdx.y + 1;      // 1..15
  int dir = gh / 48;
  int rem = gh % 48;
  int b = rem / 24, h = rem % 24;
  int tid = threadIdx.x, lane = tid & 63, w = tid >> 6;
  size_t rowbase = ((size_t)dir * 2 + b) * 1024;
  size_t trow = rowbase + (size_t)c * CLEN;
  const ushortT* cbSrc = cbg + ((size_t)((dir * 2 + b) * NCHUNK + c)) * 4096;
  const ushortT* stSrc = sinitb + ((size_t)gh * (NCHUNK - 1) + (c - 1)) * 4096;
  #pragma unroll
  for (int ph = 0; ph < 2; ++ph) {
    int base = ph * 2048 + w * 512;
    gload_lds16(cbSrc + base + lane * 8, &sCb[base]);
    gload_lds16(stSrc + base + lane * 8, &sST[base]);
  }
  __syncthreads();
  int fr = lane & 15, kq = lane >> 4;
  f32x4 accY[4] = {};
  #pragma unroll
  for (int kt = 0; kt < 2; ++kt) {
    int kk = kt * 32 + kq * 8;
    bf16x8 aC = *(const bf16x8*)&sCb[SWZ(w * 16 + fr, kk)];
    #pragma unroll
    for (int j = 0; j < 4; ++j) {
      bf16x8 bS = *(const bf16x8*)&sST[SWZ(j * 16 + fr, kk)];
      accY[j] = __builtin_amdgcn_mfma_f32_16x16x32_bf16(aC, bS, accY[j], 0, 0, 0);
    }
  }
  float cwv[4];
  #pragma unroll
  for (int r = 0; r < 4; ++r)
    cwv[r] = cwg[(trow + w * 16 + kq * 4 + r) * HH + h];
  #pragma unroll
  for (int j = 0; j < 4; ++j)
    #pragma unroll
    for (int r = 0; r < 4; ++r) {
      int t = w * 16 + kq * 4 + r, p = j * 16 + fr;
      yib[(trow + t) * DI + h * 64 + p] = f2bf(accY[j][r] * cwv[r]);
    }
}

// ---------------- +D*xs, gate silu(z), RMSNorm, -> bf16 ----------------
__global__ __launch_bounds__(192) void gate_norm_kernel(
    const ushortT* __restrict__ yb, const ushortT* __restrict__ yib,
    const ushortT* __restrict__ zxb, const ushortT* __restrict__ xcb,
    const float* __restrict__ Df, const float* __restrict__ Db,
    const float* __restrict__ nwf, const float* __restrict__ nwb,
    ushortT* __restrict__ yn) {
  __shared__ float lds[3];
  int bid = blockIdx.x;            // 0..4095 (dir*2048 + b*1024 + t)
  int dir = bid >> 11;
  int t = bid & 1023;
  const float* Dp = dir ? Db : Df;
  const float* nw = dir ? nwb : nwf;
  int tid = threadIdx.x;
  int c0 = tid * 8;
  float v[8];
  float ss = 0.f;
  {
    ushort8 yv8 = *(const ushort8*)&yb[(size_t)bid * DI + c0];
    ushort8 zv8 = *(const ushort8*)&zxb[(size_t)bid * NP1 + c0];
    ushort8 xv8 = *(const ushort8*)&xcb[(size_t)bid * CONVD + c0];
    ushort8 yi8 = {};
    bool hasI = (t >= CLEN);
    if (hasI) yi8 = *(const ushort8*)&yib[(size_t)bid * DI + c0];
    float Dv = Dp[c0 >> 6];
    #pragma unroll
    for (int e = 0; e < 8; ++e) {
      float yv = bf2f(yv8[e]) + (hasI ? bf2f(yi8[e]) : 0.f) + Dv * bf2f(xv8[e]);
      float zv = bf2f(zv8[e]);
      yv *= zv / (1.f + expf(-zv));
      v[e] = yv;
      ss += yv * yv;
    }
  }
  #pragma unroll
  for (int o = 32; o; o >>= 1) ss += __shfl_xor(ss, o, 64);
  if ((tid & 63) == 0) lds[tid >> 6] = ss;
  __syncthreads();
  float ms = (lds[0] + lds[1] + lds[2]) * (1.f / 1536.f);
  float sc = rsqrtf(ms + EPSF);
  {
    ushort8 o8;
    #pragma unroll
    for (int e = 0; e < 8; ++e) o8[e] = f2bf(v[e] * sc * nw[c0 + e]);
    *(ushort8*)&yn[(size_t)bid * DI + c0] = o8;
  }
}

// ---------------- out[t] = 2x[t] + mf[t] + mb[SEQ[t]] (mf/mb bf16) ----------------
__global__ __launch_bounds__(128) void combine_kernel(const float* __restrict__ x,
    const ushortT* __restrict__ mf, const ushortT* __restrict__ mb,
    float* __restrict__ out) {
  int bid = blockIdx.x;   // b*1024 + t
  int b = bid >> 10, t = bid & 1023;
  int st = seqmap(t);
  int tid = threadIdx.x;
  if (tid >= 96) return;
  int c0 = tid * 8;
  ushort8 fv = *(const ushort8*)&mf[(size_t)bid * DM + c0];
  ushort8 bv = *(const ushort8*)&mb[(size_t)(b * 1024 + st) * DM + c0];
  const float4 x0 = *(const float4*)&x[(size_t)bid * DM + c0];
  const float4 x1 = *(const float4*)&x[(size_t)bid * DM + c0 + 4];
  float4 o0, o1;
  o0.x = 2.f * x0.x + bf2f(fv[0]) + bf2f(bv[0]);
  o0.y = 2.f * x0.y + bf2f(fv[1]) + bf2f(bv[1]);
  o0.z = 2.f * x0.z + bf2f(fv[2]) + bf2f(bv[2]);
  o0.w = 2.f * x0.w + bf2f(fv[3]) + bf2f(bv[3]);
  o1.x = 2.f * x1.x + bf2f(fv[4]) + bf2f(bv[4]);
  o1.y = 2.f * x1.y + bf2f(fv[5]) + bf2f(bv[5]);
  o1.z = 2.f * x1.z + bf2f(fv[6]) + bf2f(bv[6]);
  o1.w = 2.f * x1.w + bf2f(fv[7]) + bf2f(bv[7]);
  *(float4*)&out[(size_t)bid * DM + c0] = o0;
  *(float4*)&out[(size_t)bid * DM + c0 + 4] = o1;
}

extern "C" void kernel_launch(void* const* d_in, const int* in_sizes, int n_in,
                              void* d_out, int out_size, void* d_ws, size_t ws_size,
                              hipStream_t stream) {
  const float* x       = (const float*)d_in[0];
  const float* f_ln_w  = (const float*)d_in[1];
  const float* f_ln_b  = (const float*)d_in[2];
  const float* f_in_w  = (const float*)d_in[3];
  const float* f_cw    = (const float*)d_in[4];
  const float* f_cb    = (const float*)d_in[5];
  const float* f_dtb   = (const float*)d_in[6];
  const float* f_alog  = (const float*)d_in[7];
  const float* f_D     = (const float*)d_in[8];
  const float* f_nw    = (const float*)d_in[9];
  const float* f_ow    = (const float*)d_in[10];
  const float* b_ln_w  = (const float*)d_in[11];
  const float* b_ln_b  = (const float*)d_in[12];
  const float* b_in_w  = (const float*)d_in[13];
  const float* b_cw    = (const float*)d_in[14];
  const float* b_cb    = (const float*)d_in[15];
  const float* b_dtb   = (const float*)d_in[16];
  const float* b_alog  = (const float*)d_in[17];
  const float* b_D     = (const float*)d_in[18];
  const float* b_nw    = (const float*)d_in[19];
  const float* b_ow    = (const float*)d_in[20];

  char* ws = (char*)d_ws;
  size_t off = 0;
  auto carve = [&](size_t bytes) -> char* {
    off = (off + 255) & ~(size_t)255;
    char* p = ws + off;
    off += bytes;
    return p;
  };
  ushortT* XLN   = (ushortT*)carve((size_t)2 * ROWS * DM * 2);
  ushortT* WP1   = (ushortT*)carve((size_t)2 * NP1 * DM * 2);
  ushortT* W2    = (ushortT*)carve((size_t)2 * DM * DI * 2);
  ushortT* ZXB   = (ushortT*)carve((size_t)2 * ROWS * NP1 * 2);
  float*   DTT   = (float*)carve((size_t)2 * ROWS * 128 * 4);
  ushortT* XCB   = (ushortT*)carve((size_t)2 * ROWS * CONVD * 2);
  float*   DTS   = (float*)carve((size_t)2 * ROWS * HH * 4);
  float*   LDA   = (float*)carve((size_t)2 * ROWS * HH * 4);
  ushortT* YB    = (ushortT*)carve((size_t)2 * ROWS * DI * 2);
  ushortT* YIB   = (ushortT*)carve((size_t)2 * ROWS * DI * 2);
  ushortT* YN    = (ushortT*)carve((size_t)2 * ROWS * DI * 2);
  ushortT* MOUTB = (ushortT*)carve((size_t)2 * ROWS * DM * 2);
  ushortT* SLOCB = (ushortT*)carve((size_t)96 * NCHUNK * 4096 * 2);
  ushortT* SINIB = (ushortT*)carve((size_t)96 * (NCHUNK - 1) * 4096 * 2);
  ushortT* CBG   = (ushortT*)carve((size_t)4 * NCHUNK * 4096 * 2);
  float*   CWG   = (float*)carve((size_t)2 * ROWS * HH * 4);

  // weight conversion (merged, vectorized)
  cvt_all_kernel<<<2048, 256, 0, stream>>>(f_in_w, b_in_w, f_ow, b_ow, WP1, W2);

  // layernorm (both dirs)
  ln_kernel<<<4096, 256, 0, stream>>>(x, f_ln_w, f_ln_b, b_ln_w, b_ln_b, XLN);

  // in_proj: [2048,768] x [3328,768]^T -> bf16 z/xBC + f32 dt tail
  gemm_bf16<1><<<dim3(NP1 / 128, ROWS / 128, 2), 256, 0, stream>>>(
      XLN, WP1, DTT, ZXB, DM, DM, DM, NP1,
      (long)ROWS * DM, (long)NP1 * DM, (long)ROWS * 128, (long)ROWS * NP1);

  // conv + dt/logdA (LDS-staged)
  conv_dt_kernel<<<dim3(8, 16, 4), 256, 0, stream>>>(ZXB, DTT, f_cw, f_cb, b_cw, b_cb,
                                                     f_dtb, f_alog, b_dtb, b_alog,
                                                     XCB, DTS, LDA);

  // chunked scan: pass 1 (SSD/MFMA), pass 2 (prefix), pass 3 (MFMA fixup)
  ssd_chunk_kernel<<<dim3(96, NCHUNK), 256, 0, stream>>>(XCB, DTS, LDA, YB, SLOCB, CWG, CBG);
  chunk_prefix_kernel<<<96, 256, 0, stream>>>(SLOCB, CWG, SINIB);
  fixup_kernel<<<dim3(96, NCHUNK - 1), 256, 0, stream>>>(CBG, SINIB, CWG, YIB);

  // gate + rmsnorm
  gate_norm_kernel<<<4096, 192, 0, stream>>>(YB, YIB, ZXB, XCB, f_D, b_D, f_nw, b_nw, YN);

  // out_proj: [2048,1536] x [768,1536]^T -> [2048,768] bf16
  gemm_bf16<0><<<dim3(DM / 128, ROWS / 128, 2), 256, 0, stream>>>(
      YN, W2, nullptr, MOUTB, DI, DI, DI, DM,
      (long)ROWS * DI, (long)DM * DI, 0, (long)ROWS * DM);

  // combine
  combine_kernel<<<2048, 128, 0, stream>>>(x, MOUTB, MOUTB + (size_t)ROWS * DM, (float*)d_out);
}

// Round 8
// 162.082 us; speedup vs baseline: 1.1548x; 1.1548x over previous
//
#include <hip/hip_runtime.h>
#include <cstdint>

#define DM    768
#define DI    1536
#define PP    64
#define HH    24
#define NN    64
#define CONVD 1664
#define DINP  3224
#define NP1   3328   // 3224 padded to 26*128
#define LL    1024
#define ROWS  2048   // BATCH*LL
#define EPSF  1e-5f
#define NCHUNK 16
#define CLEN   64
#define CSTRIPE 208

typedef unsigned short ushortT;
typedef __attribute__((ext_vector_type(8))) __bf16 bf16x8;
typedef __attribute__((ext_vector_type(8))) unsigned short ushort8;
typedef __attribute__((ext_vector_type(4))) unsigned short ushort4v;
typedef __attribute__((ext_vector_type(4))) float f32x4;

__device__ __forceinline__ int seqmap(int t) { return 1023 - 32 * (t & 31) - (t >> 5); }

__device__ __forceinline__ ushortT f2bf(float f) {
  union { float f; unsigned u; } v; v.f = f;
  unsigned r = v.u + 0x7FFF + ((v.u >> 16) & 1);
  return (ushortT)(r >> 16);
}
__device__ __forceinline__ float bf2f(ushortT b) {
  union { unsigned u; float f; } v; v.u = ((unsigned)b) << 16;
  return v.f;
}

__device__ __forceinline__ void gload_lds16(const void* g, void* l) {
  __builtin_amdgcn_global_load_lds((const __attribute__((address_space(1))) void*)g,
                                   (__attribute__((address_space(3))) void*)l, 16, 0, 0);
}

// swizzled ushort index into a 64x64 bf16 tile (row stride 64)
#define SWZ(r, c) ((r) * 64 + ((c) ^ (((r) & 7) << 3)))
// swizzled ushort index into a [128][64] bf16 tile (row stride 64)
#define SWZ64(r, c) ((r) * 64 + ((c) ^ (((r) & 7) << 3)))

// ---------------- merged weight convert (f32 -> bf16, zero-pad tail), vectorized ----------------
__global__ __launch_bounds__(256) void cvt_all_kernel(
    const float* __restrict__ fw1, const float* __restrict__ bw1,
    const float* __restrict__ fw2, const float* __restrict__ bw2,
    ushortT* __restrict__ WP1, ushortT* __restrict__ W2) {
  const long NW1 = (long)NP1 * DM, SW1 = (long)DINP * DM, NW2 = (long)DM * DI;
  const long tot8 = (2 * NW1 + 2 * NW2) >> 3;
  for (long i8 = (long)blockIdx.x * 256 + threadIdx.x; i8 < tot8; i8 += (long)gridDim.x * 256) {
    long i = i8 << 3;
    const float* src = nullptr;
    ushortT* dst;
    if (i < NW1) {
      if (i < SW1) src = fw1 + i;
      dst = WP1 + i;
    } else if (i < 2 * NW1) {
      long j = i - NW1;
      if (j < SW1) src = bw1 + j;
      dst = WP1 + i;
    } else if (i < 2 * NW1 + NW2) {
      long j = i - 2 * NW1;
      src = fw2 + j;
      dst = W2 + j;
    } else {
      long j = i - 2 * NW1 - NW2;
      src = bw2 + j;
      dst = W2 + NW2 + j;
    }
    ushort8 o = {};
    if (src) {
      float4 a = *(const float4*)src;
      float4 b2 = *(const float4*)(src + 4);
      o[0] = f2bf(a.x);  o[1] = f2bf(a.y);  o[2] = f2bf(a.z);  o[3] = f2bf(a.w);
      o[4] = f2bf(b2.x); o[5] = f2bf(b2.y); o[6] = f2bf(b2.z); o[7] = f2bf(b2.w);
    }
    *(ushort8*)dst = o;
  }
}

// ---------------- LayerNorm (both dirs; dir1 gathers via SEQ), vectorized ----------------
__global__ __launch_bounds__(192) void ln_kernel(const float* __restrict__ x,
    const float* __restrict__ wf, const float* __restrict__ bf_,
    const float* __restrict__ wb, const float* __restrict__ bb,
    ushortT* __restrict__ xln) {
  __shared__ float lds[3];
  int bid = blockIdx.x;
  int dir = bid >> 11, row = bid & 2047;
  int b = row >> 10, t = row & 1023;
  int st = dir ? seqmap(t) : t;
  const float* xr = x + (size_t)(b * 1024 + st) * DM;
  const float* w = dir ? wb : wf;
  const float* bia = dir ? bb : bf_;
  int tid = threadIdx.x;
  int c0 = tid * 4;
  float4 v = *(const float4*)&xr[c0];
  float s = v.x + v.y + v.z + v.w;
  #pragma unroll
  for (int o = 32; o; o >>= 1) s += __shfl_xor(s, o, 64);
  if ((tid & 63) == 0) lds[tid >> 6] = s;
  __syncthreads();
  float mean = (lds[0] + lds[1] + lds[2]) * (1.f / 768.f);
  __syncthreads();
  float dx = v.x - mean, dy = v.y - mean, dz = v.z - mean, dw = v.w - mean;
  float q = dx * dx + dy * dy + dz * dz + dw * dw;
  #pragma unroll
  for (int o = 32; o; o >>= 1) q += __shfl_xor(q, o, 64);
  if ((tid & 63) == 0) lds[tid >> 6] = q;
  __syncthreads();
  float var = (lds[0] + lds[1] + lds[2]) * (1.f / 768.f);
  float rs = rsqrtf(var + EPSF);
  float4 wv = *(const float4*)&w[c0];
  float4 bv = *(const float4*)&bia[c0];
  ushort4v o4 = { f2bf(dx * rs * wv.x + bv.x), f2bf(dy * rs * wv.y + bv.y),
                  f2bf(dz * rs * wv.z + bv.z), f2bf(dw * rs * wv.w + bv.w) };
  *(ushort4v*)&xln[(size_t)bid * DM + c0] = o4;
}

// ---------------- bf16 MFMA GEMM: C[M,N] = A[M,K] * B[N,K]^T ----------------
// BK=64, double-buffered LDS, counted vmcnt + raw barriers (round-6 known-good),
// T2 both-sides swizzle, T1 XCD-aware block swizzle.
// MODE 0: bf16 output to Cb. MODE 1: bf16 to Cb for n0<3200, f32 to Cf (dt tail, ld 128).
template<int MODE>
__global__ __launch_bounds__(256) void gemm_bf16(
    const ushortT* __restrict__ Aall, const ushortT* __restrict__ Ball,
    float* __restrict__ Cfall, ushortT* __restrict__ Cball,
    int K, int lda, int ldb, int ldc, long sA, long sB, long sCf, long sCb) {
  __shared__ ushortT sA2[2][128 * 64];
  __shared__ ushortT sB2[2][128 * 64];
  // T1: XCD-aware remap of flat block id (nwg % 8 == 0 for both launches)
  int gx = gridDim.x, gy = gridDim.y;
  int nwg = gx * gy * gridDim.z;
  int lid = blockIdx.x + gx * (blockIdx.y + gy * blockIdx.z);
  int cpx = nwg >> 3;
  int swz = (lid & 7) * cpx + (lid >> 3);
  int bx = swz % gx;
  int rest = swz / gx;
  int by = rest % gy, bz = rest / gy;
  const ushortT* A = Aall + (size_t)bz * sA;
  const ushortT* B = Ball + (size_t)bz * sB;
  int tid = threadIdx.x, lane = tid & 63, w = tid >> 6;
  int wm = w >> 1, wn = w & 1;
  int m0 = by * 128, n0 = bx * 128;
  int rA8 = lane >> 3;
  int cSw = ((lane & 7) << 3) ^ (((lane >> 3) & 7) << 3);   // pre-swizzled source col
  f32x4 acc[4][4] = {};
  const int NT = K >> 6;
  int fr = lane & 15, kq = lane >> 4;

  auto STAGE = [&](int bf, int kt) {
    int kc = kt * 64 + cSw;
    #pragma unroll
    for (int c2 = 0; c2 < 4; ++c2) {
      int q = w * 4 + c2;
      gload_lds16(A + (size_t)(m0 + q * 8 + rA8) * lda + kc, &sA2[bf][q * 512]);
    }
    #pragma unroll
    for (int c2 = 0; c2 < 4; ++c2) {
      int q = w * 4 + c2;
      gload_lds16(B + (size_t)(n0 + q * 8 + rA8) * ldb + kc, &sB2[bf][q * 512]);
    }
  };

  STAGE(0, 0);
  int cur = 0;
  for (int kt = 0; kt < NT; ++kt) {
    if (kt + 1 < NT) {
      STAGE(cur ^ 1, kt + 1);
      asm volatile("s_waitcnt vmcnt(8)" ::: "memory");   // tile kt's 8 loads done
    } else {
      asm volatile("s_waitcnt vmcnt(0)" ::: "memory");
    }
    __builtin_amdgcn_s_barrier();                         // all waves' tile-kt loads done
    __builtin_amdgcn_sched_barrier(0);
    #pragma unroll
    for (int ks = 0; ks < 2; ++ks) {
      int kb = ks * 32 + kq * 8;
      bf16x8 af[4], bfr[4];
      #pragma unroll
      for (int i = 0; i < 4; ++i)
        af[i] = *(const bf16x8*)&sA2[cur][SWZ64(wm * 64 + i * 16 + fr, kb)];
      #pragma unroll
      for (int j = 0; j < 4; ++j)
        bfr[j] = *(const bf16x8*)&sB2[cur][SWZ64(wn * 64 + j * 16 + fr, kb)];
      #pragma unroll
      for (int i = 0; i < 4; ++i)
        #pragma unroll
        for (int j = 0; j < 4; ++j)
          acc[i][j] = __builtin_amdgcn_mfma_f32_16x16x32_bf16(af[i], bfr[j], acc[i][j], 0, 0, 0);
    }
    asm volatile("s_waitcnt lgkmcnt(0)" ::: "memory");    // my LDS reads consumed
    __builtin_amdgcn_sched_barrier(0);
    __builtin_amdgcn_s_barrier();                         // safe to overwrite buf next iter
    cur ^= 1;
  }
  int cr = (lane >> 4) * 4, cc = lane & 15;
  if (MODE == 1 && n0 >= 3200) {
    float* Cf = Cfall + (size_t)bz * sCf;
    #pragma unroll
    for (int i = 0; i < 4; ++i)
      #pragma unroll
      for (int j = 0; j < 4; ++j) {
        float* Cp = Cf + (size_t)(m0 + wm * 64 + i * 16 + cr) * 128 + (wn * 64 + j * 16 + cc);
        #pragma unroll
        for (int r = 0; r < 4; ++r) Cp[(size_t)r * 128] = acc[i][j][r];
      }
  } else {
    ushortT* Cb = Cball + (size_t)bz * sCb;
    #pragma unroll
    for (int i = 0; i < 4; ++i)
      #pragma unroll
      for (int j = 0; j < 4; ++j) {
        ushortT* Cp = Cb + (size_t)(m0 + wm * 64 + i * 16 + cr) * ldc + (n0 + wn * 64 + j * 16 + cc);
        #pragma unroll
        for (int r = 0; r < 4; ++r) Cp[(size_t)r * ldc] = f2bf(acc[i][j][r]);
      }
  }
}

// ---------------- conv(K=4 causal, depthwise) + silu + dt/logdA, LDS-staged ----------------
// grid: (stripe 0..7, chunk 0..15, dirb 0..3); each block: 64 t x 208 channels.
__global__ __launch_bounds__(256) void conv_dt_kernel(const ushortT* __restrict__ zxb,
    const float* __restrict__ dtt,
    const float* __restrict__ cwf, const float* __restrict__ cbf,
    const float* __restrict__ cwb, const float* __restrict__ cbb,
    const float* __restrict__ dtbf, const float* __restrict__ alogf,
    const float* __restrict__ dtbb, const float* __restrict__ alogb,
    ushortT* __restrict__ xcb, float* __restrict__ dts, float* __restrict__ lda_) {
  __shared__ ushortT sZ[67][CSTRIPE];
  int stripe = blockIdx.x, chunk = blockIdx.y, dirb = blockIdx.z;
  int dir = dirb >> 1;
  int t0 = chunk * 64;
  size_t rowb = (size_t)dirb * 1024;
  const float* cw = dir ? cwb : cwf;
  const float* cb = dir ? cbb : cbf;
  int tid = threadIdx.x;
  int cbase = stripe * CSTRIPE;
  for (int idx = tid; idx < 67 * 26; idx += 256) {
    int r = idx / 26, u = idx % 26;
    int t = t0 - 3 + r;
    ushort8 v = {};
    if (t >= 0)
      v = *(const ushort8*)&zxb[(rowb + t) * NP1 + 1536 + cbase + u * 8];
    *(ushort8*)&sZ[r][u * 8] = v;
  }
  if (stripe == 0) {
    const float* dtb  = dir ? dtbb : dtbf;
    const float* alog = dir ? alogb : alogf;
    for (int i = tid; i < 64 * HH; i += 256) {
      int tt = i / HH, h = i % HH;
      size_t row = rowb + t0 + tt;
      float raw = dtt[row * 128 + h] + dtb[h];
      float dtv = raw > 20.f ? raw : log1pf(expf(raw));
      dts[row * HH + h] = dtv;
      lda_[row * HH + h] = -expf(alog[h]) * dtv;
    }
  }
  __syncthreads();
  for (int idx = tid; idx < 64 * 26; idx += 256) {
    int r = idx / 26, u = idx % 26;
    int c0 = cbase + u * 8;
    ushort8 x0 = *(const ushort8*)&sZ[r][u * 8];
    ushort8 x1 = *(const ushort8*)&sZ[r + 1][u * 8];
    ushort8 x2 = *(const ushort8*)&sZ[r + 2][u * 8];
    ushort8 x3 = *(const ushort8*)&sZ[r + 3][u * 8];
    ushort8 o;
    #pragma unroll
    for (int e = 0; e < 8; ++e) {
      int c = c0 + e;
      float acc = cb[c] + bf2f(x0[e]) * cw[c * 4 + 0] + bf2f(x1[e]) * cw[c * 4 + 1]
                + bf2f(x2[e]) * cw[c * 4 + 2] + bf2f(x3[e]) * cw[c * 4 + 3];
      o[e] = f2bf(acc / (1.f + expf(-acc)));
    }
    *(ushort8*)&xcb[(rowb + t0 + r) * CONVD + c0] = o;
  }
}

// ---------------- pass 1 (SSD form): block per (gh, chunk) ----------------
__global__ __launch_bounds__(256) void ssd_chunk_kernel(const ushortT* __restrict__ xcb,
    const float* __restrict__ dts, const float* __restrict__ lda_,
    ushortT* __restrict__ yb, ushortT* __restrict__ slocb, float* __restrict__ cwg,
    ushortT* __restrict__ cbg) {
  __shared__ ushortT sCb[4096];   // [t][n]
  __shared__ ushortT sBb[4096];   // [s][n]
  __shared__ ushortT sBT[4096];   // [n][t]  (weighted)
  __shared__ ushortT sXT[4096];   // [p][t]
  __shared__ ushortT sMb[4096];   // [t][s]
  __shared__ float clog[64];
  __shared__ float dt64[64];
  __shared__ float wv64[64];
  int gh = blockIdx.x;                 // dir*48 + b*24 + h
  int c  = blockIdx.y;                 // chunk
  int dir = gh / 48;
  int rem = gh % 48;
  int b = rem / 24, h = rem % 24;
  int tid = threadIdx.x, lane = tid & 63;
  int w = tid >> 6;
  size_t rowbase = ((size_t)dir * 2 + b) * 1024;
  size_t trow = rowbase + (size_t)c * CLEN;

  // ---- phase 1: stage C, B (ushort8); X^T via b64 vectorized transpose ----
  #pragma unroll
  for (int it2 = 0; it2 < 2; ++it2) {
    int idx2 = it2 * 256 + tid;
    int r = idx2 >> 3, c8 = (idx2 & 7) << 3;
    const ushortT* xrow = xcb + (trow + r) * CONVD;
    *(ushort8*)&sCb[SWZ(r, c8)] = *(const ushort8*)&xrow[1600 + c8];
    *(ushort8*)&sBb[SWZ(r, c8)] = *(const ushort8*)&xrow[1536 + c8];
  }
  {
    int p = lane;
    #pragma unroll
    for (int q = 0; q < 4; ++q) {
      int t4 = w * 16 + q * 4;
      ushortT a0 = xcb[(trow + t4 + 0) * CONVD + h * 64 + p];
      ushortT a1 = xcb[(trow + t4 + 1) * CONVD + h * 64 + p];
      ushortT a2 = xcb[(trow + t4 + 2) * CONVD + h * 64 + p];
      ushortT a3 = xcb[(trow + t4 + 3) * CONVD + h * 64 + p];
      int cT = t4 ^ ((p & 7) << 3);
      ushort4v v4 = {a0, a1, a2, a3};
      *(ushort4v*)&sXT[p * 64 + cT] = v4;
    }
  }
  if (tid < 64) {
    float ld = lda_[(trow + tid) * HH + h];
    float dtv = dts[(trow + tid) * HH + h];
    float v = ld;
    #pragma unroll
    for (int o = 1; o < 64; o <<= 1) {
      float u = __shfl_up(v, o, 64);
      if (tid >= o) v += u;
    }
    float tot = __shfl(v, 63, 64);
    clog[tid] = v;
    dt64[tid] = dtv;
    wv64[tid] = dtv * __expf(tot - v);
    cwg[(trow + tid) * HH + h] = __expf(v);
  }
  __syncthreads();

  // dump C tile once per (dir,b,chunk) for the fixup pass
  if (h == 0) {
    ushortT* dst = cbg + ((size_t)((dir * 2 + b) * NCHUNK + c)) * 4096;
    for (int idx = tid; idx < 4096; idx += 256) dst[idx] = sCb[idx];
  }

  int fr = lane & 15, kq = lane >> 4;

  // ---- phase 2: weighted B^T (b64 transpose); G = C.B^T; decay -> M(bf16) ----
  {
    int n = lane;
    #pragma unroll
    for (int q = 0; q < 4; ++q) {
      int s4 = w * 16 + q * 4;
      float b0 = bf2f(sBb[SWZ(s4 + 0, n)]) * wv64[s4 + 0];
      float b1 = bf2f(sBb[SWZ(s4 + 1, n)]) * wv64[s4 + 1];
      float b2 = bf2f(sBb[SWZ(s4 + 2, n)]) * wv64[s4 + 2];
      float b3 = bf2f(sBb[SWZ(s4 + 3, n)]) * wv64[s4 + 3];
      int cT = s4 ^ ((n & 7) << 3);
      ushort4v v4 = {f2bf(b0), f2bf(b1), f2bf(b2), f2bf(b3)};
      *(ushort4v*)&sBT[n * 64 + cT] = v4;
    }
  }
  f32x4 accG[4] = {};
  #pragma unroll
  for (int kt = 0; kt < 2; ++kt) {
    int kk = kt * 32 + kq * 8;
    bf16x8 af = *(const bf16x8*)&sCb[SWZ(w * 16 + fr, kk)];
    #pragma unroll
    for (int j = 0; j < 4; ++j) {
      bf16x8 bf_ = *(const bf16x8*)&sBb[SWZ(j * 16 + fr, kk)];
      accG[j] = __builtin_amdgcn_mfma_f32_16x16x32_bf16(af, bf_, accG[j], 0, 0, 0);
    }
  }
  #pragma unroll
  for (int j = 0; j < 4; ++j) {
    int s = j * 16 + fr;
    float cls = clog[s], dtv = dt64[s];
    #pragma unroll
    for (int r = 0; r < 4; ++r) {
      int t = w * 16 + kq * 4 + r;
      float dec = (s <= t) ? __expf(clog[t] - cls) * dtv : 0.f;
      sMb[SWZ(t, s)] = f2bf(accG[j][r] * dec);
    }
  }
  __syncthreads();

  // ---- phase 3: Y = M.X ; S = wB^T.X (shared X fragments) ----
  f32x4 accY[4] = {}, accS[4] = {};
  #pragma unroll
  for (int kt = 0; kt < 2; ++kt) {
    int kk = kt * 32 + kq * 8;
    bf16x8 aM = *(const bf16x8*)&sMb[SWZ(w * 16 + fr, kk)];
    bf16x8 aB = *(const bf16x8*)&sBT[SWZ(w * 16 + fr, kk)];
    #pragma unroll
    for (int j = 0; j < 4; ++j) {
      bf16x8 bx = *(const bf16x8*)&sXT[SWZ(j * 16 + fr, kk)];
      accY[j] = __builtin_amdgcn_mfma_f32_16x16x32_bf16(aM, bx, accY[j], 0, 0, 0);
      accS[j] = __builtin_amdgcn_mfma_f32_16x16x32_bf16(aB, bx, accS[j], 0, 0, 0);
    }
  }
  ushortT* spb = slocb + ((size_t)gh * NCHUNK + c) * 4096;
  #pragma unroll
  for (int j = 0; j < 4; ++j) {
    #pragma unroll
    for (int r = 0; r < 4; ++r) {
      int t = w * 16 + kq * 4 + r;        // row (t for Y, n for S)
      int p = j * 16 + fr;                // col
      yb[(trow + t) * DI + h * 64 + p] = f2bf(accY[j][r]);
      spb[t * 64 + p] = f2bf(accS[j][r]);
    }
  }
}

// ---------------- pass 2: serial prefix over chunk states (96 blocks) ----------------
__global__ __launch_bounds__(256) void chunk_prefix_kernel(
    const ushortT* __restrict__ slocb, const float* __restrict__ cwg,
    ushortT* __restrict__ sinitb) {
  __shared__ float ldsT[64 * 65];
  int gh = blockIdx.x;
  int dir = gh / 48;
  int rem = gh % 48;
  int b = rem / 24, h = rem % 24;
  int tid = threadIdx.x;
  size_t rowbase = ((size_t)dir * 2 + b) * 1024;
  float R[16];
  #pragma unroll
  for (int j = 0; j < 16; ++j) R[j] = 0.f;
  for (int c = 1; c < NCHUNK; ++c) {
    float W = cwg[(rowbase + (size_t)c * CLEN - 1) * HH + h];
    const ushortT* slot = slocb + ((size_t)gh * NCHUNK + (c - 1)) * 4096;
    #pragma unroll
    for (int j = 0; j < 16; ++j) {
      int idx = j * 256 + tid, n = idx >> 6, p = idx & 63;
      R[j] = __builtin_fmaf(R[j], W, bf2f(slot[idx]));
      ldsT[n * 65 + p] = R[j];
    }
    __syncthreads();
    ushortT* outp = sinitb + ((size_t)gh * (NCHUNK - 1) + (c - 1)) * 4096;
    #pragma unroll
    for (int j = 0; j < 16; ++j) {
      int idx = j * 256 + tid, p = idx >> 6, n = idx & 63;
      outp[SWZ(p, n)] = f2bf(ldsT[n * 65 + p]);
    }
    __syncthreads();
  }
}

// ---------------- pass 3 (MFMA): YI[t,p] = cw[t] * (C_t . S_init) ----------------
__global__ __launch_bounds__(256) void fixup_kernel(
    const ushortT* __restrict__ cbg, const ushortT* __restrict__ sinitb,
    const float* __restrict__ cwg, ushortT* __restrict__ yib) {
  __shared__ ushortT sCb[4096];
  __shared__ ushortT sST[4096];
  int gh = blockIdx.x;
  int c = blockIdx.y + 1;      // 1..15
  int dir = gh / 48;
  int rem = gh % 48;
  int b = rem / 24, h = rem % 24;
  int tid = threadIdx.x, lane = tid & 63, w = tid >> 6;
  size_t rowbase = ((size_t)dir * 2 + b) * 1024;
  size_t trow = rowbase + (size_t)c * CLEN;
  const ushortT* cbSrc = cbg + ((size_t)((dir * 2 + b) * NCHUNK + c)) * 4096;
  const ushortT* stSrc = sinitb + ((size_t)gh * (NCHUNK - 1) + (c - 1)) * 4096;
  #pragma unroll
  for (int ph = 0; ph < 2; ++ph) {
    int base = ph * 2048 + w * 512;
    gload_lds16(cbSrc + base + lane * 8, &sCb[base]);
    gload_lds16(stSrc + base + lane * 8, &sST[base]);
  }
  __syncthreads();
  int fr = lane & 15, kq = lane >> 4;
  f32x4 accY[4] = {};
  #pragma unroll
  for (int kt = 0; kt < 2; ++kt) {
    int kk = kt * 32 + kq * 8;
    bf16x8 aC = *(const bf16x8*)&sCb[SWZ(w * 16 + fr, kk)];
    #pragma unroll
    for (int j = 0; j < 4; ++j) {
      bf16x8 bS = *(const bf16x8*)&sST[SWZ(j * 16 + fr, kk)];
      accY[j] = __builtin_amdgcn_mfma_f32_16x16x32_bf16(aC, bS, accY[j], 0, 0, 0);
    }
  }
  float cwv[4];
  #pragma unroll
  for (int r = 0; r < 4; ++r)
    cwv[r] = cwg[(trow + w * 16 + kq * 4 + r) * HH + h];
  #pragma unroll
  for (int j = 0; j < 4; ++j)
    #pragma unroll
    for (int r = 0; r < 4; ++r) {
      int t = w * 16 + kq * 4 + r, p = j * 16 + fr;
      yib[(trow + t) * DI + h * 64 + p] = f2bf(accY[j][r] * cwv[r]);
    }
}

// ---------------- +D*xs, gate silu(z), RMSNorm, -> bf16 ----------------
__global__ __launch_bounds__(192) void gate_norm_kernel(
    const ushortT* __restrict__ yb, const ushortT* __restrict__ yib,
    const ushortT* __restrict__ zxb, const ushortT* __restrict__ xcb,
    const float* __restrict__ Df, const float* __restrict__ Db,
    const float* __restrict__ nwf, const float* __restrict__ nwb,
    ushortT* __restrict__ yn) {
  __shared__ float lds[3];
  int bid = blockIdx.x;            // 0..4095 (dir*2048 + b*1024 + t)
  int dir = bid >> 11;
  int t = bid & 1023;
  const float* Dp = dir ? Db : Df;
  const float* nw = dir ? nwb : nwf;
  int tid = threadIdx.x;
  int c0 = tid * 8;
  float v[8];
  float ss = 0.f;
  {
    ushort8 yv8 = *(const ushort8*)&yb[(size_t)bid * DI + c0];
    ushort8 zv8 = *(const ushort8*)&zxb[(size_t)bid * NP1 + c0];
    ushort8 xv8 = *(const ushort8*)&xcb[(size_t)bid * CONVD + c0];
    ushort8 yi8 = {};
    bool hasI = (t >= CLEN);
    if (hasI) yi8 = *(const ushort8*)&yib[(size_t)bid * DI + c0];
    float Dv = Dp[c0 >> 6];
    #pragma unroll
    for (int e = 0; e < 8; ++e) {
      float yv = bf2f(yv8[e]) + (hasI ? bf2f(yi8[e]) : 0.f) + Dv * bf2f(xv8[e]);
      float zv = bf2f(zv8[e]);
      yv *= zv / (1.f + expf(-zv));
      v[e] = yv;
      ss += yv * yv;
    }
  }
  #pragma unroll
  for (int o = 32; o; o >>= 1) ss += __shfl_xor(ss, o, 64);
  if ((tid & 63) == 0) lds[tid >> 6] = ss;
  __syncthreads();
  float ms = (lds[0] + lds[1] + lds[2]) * (1.f / 1536.f);
  float sc = rsqrtf(ms + EPSF);
  {
    ushort8 o8;
    #pragma unroll
    for (int e = 0; e < 8; ++e) o8[e] = f2bf(v[e] * sc * nw[c0 + e]);
    *(ushort8*)&yn[(size_t)bid * DI + c0] = o8;
  }
}

// ---------------- out[t] = 2x[t] + mf[t] + mb[SEQ[t]] (mf/mb bf16) ----------------
__global__ __launch_bounds__(128) void combine_kernel(const float* __restrict__ x,
    const ushortT* __restrict__ mf, const ushortT* __restrict__ mb,
    float* __restrict__ out) {
  int bid = blockIdx.x;   // b*1024 + t
  int b = bid >> 10, t = bid & 1023;
  int st = seqmap(t);
  int tid = threadIdx.x;
  if (tid >= 96) return;
  int c0 = tid * 8;
  ushort8 fv = *(const ushort8*)&mf[(size_t)bid * DM + c0];
  ushort8 bv = *(const ushort8*)&mb[(size_t)(b * 1024 + st) * DM + c0];
  const float4 x0 = *(const float4*)&x[(size_t)bid * DM + c0];
  const float4 x1 = *(const float4*)&x[(size_t)bid * DM + c0 + 4];
  float4 o0, o1;
  o0.x = 2.f * x0.x + bf2f(fv[0]) + bf2f(bv[0]);
  o0.y = 2.f * x0.y + bf2f(fv[1]) + bf2f(bv[1]);
  o0.z = 2.f * x0.z + bf2f(fv[2]) + bf2f(bv[2]);
  o0.w = 2.f * x0.w + bf2f(fv[3]) + bf2f(bv[3]);
  o1.x = 2.f * x1.x + bf2f(fv[4]) + bf2f(bv[4]);
  o1.y = 2.f * x1.y + bf2f(fv[5]) + bf2f(bv[5]);
  o1.z = 2.f * x1.z + bf2f(fv[6]) + bf2f(bv[6]);
  o1.w = 2.f * x1.w + bf2f(fv[7]) + bf2f(bv[7]);
  *(float4*)&out[(size_t)bid * DM + c0] = o0;
  *(float4*)&out[(size_t)bid * DM + c0 + 4] = o1;
}

extern "C" void kernel_launch(void* const* d_in, const int* in_sizes, int n_in,
                              void* d_out, int out_size, void* d_ws, size_t ws_size,
                              hipStream_t stream) {
  const float* x       = (const float*)d_in[0];
  const float* f_ln_w  = (const float*)d_in[1];
  const float* f_ln_b  = (const float*)d_in[2];
  const float* f_in_w  = (const float*)d_in[3];
  const float* f_cw    = (const float*)d_in[4];
  const float* f_cb    = (const float*)d_in[5];
  const float* f_dtb   = (const float*)d_in[6];
  const float* f_alog  = (const float*)d_in[7];
  const float* f_D     = (const float*)d_in[8];
  const float* f_nw    = (const float*)d_in[9];
  const float* f_ow    = (const float*)d_in[10];
  const float* b_ln_w  = (const float*)d_in[11];
  const float* b_ln_b  = (const float*)d_in[12];
  const float* b_in_w  = (const float*)d_in[13];
  const float* b_cw    = (const float*)d_in[14];
  const float* b_cb    = (const float*)d_in[15];
  const float* b_dtb   = (const float*)d_in[16];
  const float* b_alog  = (const float*)d_in[17];
  const float* b_D     = (const float*)d_in[18];
  const float* b_nw    = (const float*)d_in[19];
  const float* b_ow    = (const float*)d_in[20];

  char* ws = (char*)d_ws;
  size_t off = 0;
  auto carve = [&](size_t bytes) -> char* {
    off = (off + 255) & ~(size_t)255;
    char* p = ws + off;
    off += bytes;
    return p;
  };
  ushortT* XLN   = (ushortT*)carve((size_t)2 * ROWS * DM * 2);
  ushortT* WP1   = (ushortT*)carve((size_t)2 * NP1 * DM * 2);
  ushortT* W2    = (ushortT*)carve((size_t)2 * DM * DI * 2);
  ushortT* ZXB   = (ushortT*)carve((size_t)2 * ROWS * NP1 * 2);
  float*   DTT   = (float*)carve((size_t)2 * ROWS * 128 * 4);
  ushortT* XCB   = (ushortT*)carve((size_t)2 * ROWS * CONVD * 2);
  float*   DTS   = (float*)carve((size_t)2 * ROWS * HH * 4);
  float*   LDA   = (float*)carve((size_t)2 * ROWS * HH * 4);
  ushortT* YB    = (ushortT*)carve((size_t)2 * ROWS * DI * 2);
  ushortT* YIB   = (ushortT*)carve((size_t)2 * ROWS * DI * 2);
  ushortT* YN    = (ushortT*)carve((size_t)2 * ROWS * DI * 2);
  ushortT* MOUTB = (ushortT*)carve((size_t)2 * ROWS * DM * 2);
  ushortT* SLOCB = (ushortT*)carve((size_t)96 * NCHUNK * 4096 * 2);
  ushortT* SINIB = (ushortT*)carve((size_t)96 * (NCHUNK - 1) * 4096 * 2);
  ushortT* CBG   = (ushortT*)carve((size_t)4 * NCHUNK * 4096 * 2);
  float*   CWG   = (float*)carve((size_t)2 * ROWS * HH * 4);

  // weight conversion (merged, vectorized)
  cvt_all_kernel<<<2048, 256, 0, stream>>>(f_in_w, b_in_w, f_ow, b_ow, WP1, W2);

  // layernorm (both dirs, vectorized)
  ln_kernel<<<4096, 192, 0, stream>>>(x, f_ln_w, f_ln_b, b_ln_w, b_ln_b, XLN);

  // in_proj: [2048,768] x [3328,768]^T -> bf16 z/xBC + f32 dt tail
  gemm_bf16<1><<<dim3(NP1 / 128, ROWS / 128, 2), 256, 0, stream>>>(
      XLN, WP1, DTT, ZXB, DM, DM, DM, NP1,
      (long)ROWS * DM, (long)NP1 * DM, (long)ROWS * 128, (long)ROWS * NP1);

  // conv + dt/logdA (LDS-staged)
  conv_dt_kernel<<<dim3(8, 16, 4), 256, 0, stream>>>(ZXB, DTT, f_cw, f_cb, b_cw, b_cb,
                                                     f_dtb, f_alog, b_dtb, b_alog,
                                                     XCB, DTS, LDA);

  // chunked scan: pass 1 (SSD/MFMA), pass 2 (prefix), pass 3 (MFMA fixup)
  ssd_chunk_kernel<<<dim3(96, NCHUNK), 256, 0, stream>>>(XCB, DTS, LDA, YB, SLOCB, CWG, CBG);
  chunk_prefix_kernel<<<96, 256, 0, stream>>>(SLOCB, CWG, SINIB);
  fixup_kernel<<<dim3(96, NCHUNK - 1), 256, 0, stream>>>(CBG, SINIB, CWG, YIB);

  // gate + rmsnorm
  gate_norm_kernel<<<4096, 192, 0, stream>>>(YB, YIB, ZXB, XCB, f_D, b_D, f_nw, b_nw, YN);

  // out_proj: [2048,1536] x [768,1536]^T -> [2048,768] bf16
  gemm_bf16<0><<<dim3(DM / 128, ROWS / 128, 2), 256, 0, stream>>>(
      YN, W2, nullptr, MOUTB, DI, DI, DI, DM,
      (long)ROWS * DI, (long)DM * DI, 0, (long)ROWS * DM);

  // combine
  combine_kernel<<<2048, 128, 0, stream>>>(x, MOUTB, MOUTB + (size_t)ROWS * DM, (float*)d_out);
}